// Round 3
// baseline (333.548 us; speedup 1.0000x reference)
//
#include <hip/hip_runtime.h>

typedef unsigned short u16;
typedef unsigned int   u32;
typedef __bf16 v8bf __attribute__((ext_vector_type(8)));
typedef float  v4f  __attribute__((ext_vector_type(4)));

#define INV_SQRT_W   0.044194173824159216f   // 1/sqrt(512)
#define INV_SQRT_KKC 0.029462782549439483f   // 1/sqrt(3*3*128)
#define LRELU_GAIN   1.4142135623730951f

__device__ __forceinline__ u16 f2bf(float f) {
    u32 u = __float_as_uint(f);
    u = (u + 0x7fffu + ((u >> 16) & 1u)) >> 16;   // RNE
    return (u16)u;
}

__device__ __forceinline__ void glds16(const u16* g, u16* l) {
    __builtin_amdgcn_global_load_lds(
        (const __attribute__((address_space(1))) void*)g,
        (__attribute__((address_space(3))) void*)l, 16, 0, 0);
}

// ---------------- kernel S: s[n,i] = z @ (aw/sqrt(512)) + ab ----------------
__global__ void k_s(const float* __restrict__ dlat,
                    const float* __restrict__ aw,
                    const float* __restrict__ ab,
                    const int*   __restrict__ lidx,
                    float* __restrict__ s_out)
{
    const int n   = blockIdx.x;      // 8
    const int tid = threadIdx.x;     // 256
    const int i   = tid & 127, kh = tid >> 7;
    const int li  = lidx[0];
    const float* z = dlat + (n * 16 + li) * 512 + kh * 256;
    const float* a = aw + kh * 256 * 128 + i;
    float a0 = 0.f, a1 = 0.f, a2 = 0.f, a3 = 0.f;
    for (int k = 0; k < 256; k += 4) {
        a0 += z[k + 0] * a[(k + 0) * 128];
        a1 += z[k + 1] * a[(k + 1) * 128];
        a2 += z[k + 2] * a[(k + 2) * 128];
        a3 += z[k + 3] * a[(k + 3) * 128];
    }
    __shared__ float part[256];
    part[tid] = a0 + a1 + a2 + a3;
    __syncthreads();
    if (tid < 128)
        s_out[n * 128 + i] = (part[i] + part[i + 128]) * INV_SQRT_W + ab[i];
}

// ---------------- kernel W2: W2[i,o] = sum_t (cw[t,i,o]*inv)^2 ----------------
__global__ void k_w2(const float* __restrict__ cw, float* __restrict__ W2)
{
    const int idx = blockIdx.x * 256 + threadIdx.x;   // 16384 = i*128+o
    float acc = 0.f;
    #pragma unroll
    for (int t = 0; t < 9; ++t) {
        float w = cw[t * 16384 + idx];
        acc += w * w;
    }
    W2[idx] = acc * (INV_SQRT_KKC * INV_SQRT_KKC);
}

// ---------------- kernel D: d[n,o] = rsqrt(sum_i W2[i,o]*s2[n,i] + 1e-8) ----------------
__global__ void k_d(const float* __restrict__ W2,
                    const float* __restrict__ s_buf,
                    float* __restrict__ d_out)
{
    const int n = blockIdx.x;   // 8
    const int o = threadIdx.x;  // 128
    __shared__ float s2[128];
    float sv = s_buf[n * 128 + o];
    s2[o] = sv * sv;
    __syncthreads();
    float acc = 1e-8f;
    #pragma unroll 4
    for (int i = 0; i < 128; ++i)
        acc += W2[i * 128 + o] * s2[i];
    d_out[n * 128 + o] = 1.0f / sqrtf(acc);
}

// -------- kernel WMOD: pre-swizzled bf16 stage blocks for global_load_lds --------
// block b = n*18 + s, s = tap*2 + half. 16KB block = [o:128][i_local:64] bf16,
// element slot = (o<<6) + (i_local ^ ((o&7)<<3))  (XOR-swizzled, identity under glds)
__global__ void k_wmod(const float* __restrict__ cw,
                       const float* __restrict__ s_buf,
                       const float* __restrict__ d_buf,
                       u16* __restrict__ wmod)
{
    const int b    = blockIdx.x;         // 144
    const int n    = b / 18;
    const int s    = b - n * 18;
    const int tap  = s >> 1, half = s & 1;
    const int tid  = threadIdx.x;        // 256
    __shared__ float tile[64][132];
    __shared__ float dsh[128], ssh[64];
    const float* src = cw + (size_t)(tap * 128 + half * 64) * 128;
    for (int it = 0; it < 32; ++it) {
        int idx = it * 256 + tid;            // 8192
        tile[idx >> 7][idx & 127] = src[idx];
    }
    if (tid < 128) dsh[tid] = d_buf[n * 128 + tid];
    if (tid < 64)  ssh[tid] = s_buf[n * 128 + half * 64 + tid] * INV_SQRT_KKC;
    __syncthreads();
    u16* wt = wmod + ((size_t)b << 13);
    #pragma unroll
    for (int rep = 0; rep < 4; ++rep) {
        int chunk = rep * 256 + tid;         // 1024
        int o = chunk >> 3, i8 = chunk & 7;
        float dv = dsh[o];
        u32 pk[4];
        #pragma unroll
        for (int jj = 0; jj < 4; ++jj) {
            int il = i8 * 8 + jj * 2;
            float v0 = tile[il][o]     * ssh[il]     * dv;
            float v1 = tile[il + 1][o] * ssh[il + 1] * dv;
            pk[jj] = (u32)f2bf(v0) | ((u32)f2bf(v1) << 16);
        }
        int el = (o << 6) + ((i8 << 3) ^ ((o & 7) << 3));
        *(uint4*)&wt[el] = *(uint4*)pk;
    }
}

// ---------------- kernel CONV: implicit-GEMM 3x3 conv ----------------
// 128 threads = 2 waves; block tile 128 px (8h x 16w) x 128 cout.
// Each wave: 128 px x 64 cout = 8 M-frags x 4 N-frags (acc[8][4], 128 VGPR).
// Per kk: 12 ds_read_b128 feed 32 MFMAs (384 B/MFMA -> MFMA-bound).
__global__ __launch_bounds__(128, 1) void k_conv(
    const float* __restrict__ x,
    const float* __restrict__ noise,
    const float* __restrict__ conv_b,
    const float* __restrict__ nstr,
    const u16*   __restrict__ wmod,
    float* __restrict__ out)
{
    __shared__ __align__(16) u16 xs[23040];       // [q=rr*18+cc][128], XOR-swizzled
    __shared__ __align__(16) u16 wsh[2][8192];    // double-buffered 16KB weight stages

    const int bid0 = blockIdx.x;
    const int bid  = ((bid0 & 7) << 9) + (bid0 >> 3);   // XCD swizzle (4096%8==0, bijective)
    const int n   = bid >> 9;
    const int hb  = (bid >> 4) & 31;
    const int wb  = bid & 15;
    const int h0  = hb << 3, w0 = wb << 4;

    const int tid  = threadIdx.x;      // 0..127
    const int lane = tid & 63;
    const int wq   = tid >> 6;         // wave id = cout half (0..1)
    const int lr   = lane & 15;
    const int kg   = lane >> 4;

    // ---- stage X halo tile (10 x 18 x 128) fp32 -> bf16, swizzled ----
    for (int t = tid; t < 2880; t += 128) {
        int q  = t >> 4, k8 = t & 15;
        int rr = q / 18, cc = q - rr * 18;
        int gh = h0 + rr - 1, gw = w0 + cc - 1;
        float v0 = 0.f, v1 = 0.f, v2 = 0.f, v3 = 0.f, v4 = 0.f, v5 = 0.f, v6 = 0.f, v7 = 0.f;
        if ((unsigned)gh < 256u && (unsigned)gw < 256u) {
            const float* src = x + (size_t)((((n << 8) + gh) << 8) + gw) * 128 + (k8 << 3);
            float4 fa = *(const float4*)(src);
            float4 fb = *(const float4*)(src + 4);
            v0 = fa.x; v1 = fa.y; v2 = fa.z; v3 = fa.w;
            v4 = fb.x; v5 = fb.y; v6 = fb.z; v7 = fb.w;
        }
        uint4 pk;
        pk.x = (u32)f2bf(v0) | ((u32)f2bf(v1) << 16);
        pk.y = (u32)f2bf(v2) | ((u32)f2bf(v3) << 16);
        pk.z = (u32)f2bf(v4) | ((u32)f2bf(v5) << 16);
        pk.w = (u32)f2bf(v6) | ((u32)f2bf(v7) << 16);
        int dst = (q << 7) + ((k8 << 3) ^ ((q & 7) << 3));
        *(uint4*)&xs[dst] = pk;
    }

    // ---- prologue: async-stage weight stage 0 into wsh[0] ----
    const u16* wn = wmod + ((size_t)(n * 18) << 13);
    #pragma unroll
    for (int t = 0; t < 8; ++t) {
        int chunk = (t << 1) + wq;
        glds16(wn + (chunk << 9) + (lane << 3), &wsh[0][chunk << 9]);
    }

    v4f acc[8][4];
    #pragma unroll
    for (int a = 0; a < 8; ++a)
        #pragma unroll
        for (int b2 = 0; b2 < 4; ++b2) {
            v4f zz = {0.f, 0.f, 0.f, 0.f};
            acc[a][b2] = zz;
        }

    __syncthreads();   // xs ready + wsh[0] landed

    #pragma unroll 1
    for (int s = 0; s < 18; ++s) {
        const int c = s & 1;
        if (s < 17) {   // prefetch next stage into the buffer freed at last barrier
            const u16* sb = wn + ((size_t)(s + 1) << 13);
            #pragma unroll
            for (int t = 0; t < 8; ++t) {
                int chunk = (t << 1) + wq;
                glds16(sb + (chunk << 9) + (lane << 3), &wsh[c ^ 1][chunk << 9]);
            }
        }
        const int tap = s >> 1;
        const int th = tap / 3, tw = tap - th * 3;
        const int hb64 = (s & 1) << 6;
        #pragma unroll
        for (int kk = 0; kk < 2; ++kk) {
            v8bf af[8], bf_[4];
            const int koff = (kk << 5) + (kg << 3);
            const int xoff = hb64 + koff;
            #pragma unroll
            for (int mi = 0; mi < 8; ++mi) {
                int q = (mi + th) * 18 + lr + tw;
                af[mi] = *(const v8bf*)&xs[(q << 7) + (xoff ^ ((q & 7) << 3))];
            }
            #pragma unroll
            for (int ni = 0; ni < 4; ++ni) {
                int o = wq * 64 + ni * 16 + lr;
                bf_[ni] = *(const v8bf*)&wsh[c][(o << 6) + (koff ^ ((o & 7) << 3))];
            }
            #pragma unroll
            for (int mi = 0; mi < 8; ++mi)
                #pragma unroll
                for (int ni = 0; ni < 4; ++ni)
                    acc[mi][ni] = __builtin_amdgcn_mfma_f32_16x16x32_bf16(
                        af[mi], bf_[ni], acc[mi][ni], 0, 0, 0);
        }
        __syncthreads();   // waves done with wsh[c]; wsh[c^1] loads drained
    }

    // ---- epilogue: + noise*strength + bias, lrelu * sqrt(2) ----
    const float ns = nstr[0];
    #pragma unroll
    for (int mi = 0; mi < 8; ++mi) {
        const int h = h0 + mi;
        #pragma unroll
        for (int j = 0; j < 4; ++j) {
            const int w  = w0 + kg * 4 + j;
            const float nz = noise[((n << 8) + h) * 256 + w] * ns;
            float* orow = out + (size_t)((((n << 8) + h) << 8) + w) * 128;
            #pragma unroll
            for (int ni = 0; ni < 4; ++ni) {
                const int cout = wq * 64 + ni * 16 + lr;
                float v = acc[mi][ni][j] + nz + conv_b[cout];
                v = (v < 0.f ? 0.2f * v : v) * LRELU_GAIN;
                orow[cout] = v;
            }
        }
    }
}

extern "C" void kernel_launch(void* const* d_in, const int* in_sizes, int n_in,
                              void* d_out, int out_size, void* d_ws, size_t ws_size,
                              hipStream_t stream) {
    const float* x     = (const float*)d_in[0];
    const float* dlat  = (const float*)d_in[1];
    const float* noise = (const float*)d_in[2];
    const float* aw    = (const float*)d_in[3];
    const float* ab    = (const float*)d_in[4];
    const float* cw    = (const float*)d_in[5];
    const float* cb    = (const float*)d_in[6];
    const float* nstr  = (const float*)d_in[7];
    const int*   lidx  = (const int*)d_in[8];
    float* out = (float*)d_out;

    float* s_buf = (float*)d_ws;                               // 4KB
    float* d_buf = (float*)((char*)d_ws + 4096);               // 4KB
    // W2 (64KB) aliases the wmod region: k_d finishes before k_wmod writes (stream order)
    float* W2    = (float*)((char*)d_ws + 8192);
    u16*   wmod  = (u16*)((char*)d_ws + 8192);                 // 8*18*8192*2B = 2.25MB

    k_w2  <<<64,  256, 0, stream>>>(cw, W2);
    k_s   <<<8,   256, 0, stream>>>(dlat, aw, ab, lidx, s_buf);
    k_d   <<<8,   128, 0, stream>>>(W2, s_buf, d_buf);
    k_wmod<<<144, 256, 0, stream>>>(cw, s_buf, d_buf, wmod);
    k_conv<<<4096,128, 0, stream>>>(x, noise, cb, nstr, wmod, out);
}

// Round 4
// 229.587 us; speedup vs baseline: 1.4528x; 1.4528x over previous
//
#include <hip/hip_runtime.h>

typedef unsigned short u16;
typedef unsigned int   u32;
typedef __bf16 v8bf __attribute__((ext_vector_type(8)));
typedef float  v4f  __attribute__((ext_vector_type(4)));

#define INV_SQRT_W   0.044194173824159216f   // 1/sqrt(512)
#define INV_SQRT_KKC 0.029462782549439483f   // 1/sqrt(3*3*128)
#define LRELU_GAIN   1.4142135623730951f

__device__ __forceinline__ u16 f2bf(float f) {
    u32 u = __float_as_uint(f);
    u = (u + 0x7fffu + ((u >> 16) & 1u)) >> 16;   // RNE
    return (u16)u;
}

__device__ __forceinline__ void glds16(const u16* g, u16* l) {
    __builtin_amdgcn_global_load_lds(
        (const __attribute__((address_space(1))) void*)g,
        (__attribute__((address_space(3))) void*)l, 16, 0, 0);
}

// ---------------- kernel S: s[n,i] = z @ (aw/sqrt(512)) + ab ----------------
__global__ void k_s(const float* __restrict__ dlat,
                    const float* __restrict__ aw,
                    const float* __restrict__ ab,
                    const int*   __restrict__ lidx,
                    float* __restrict__ s_out)
{
    const int n   = blockIdx.x;      // 8
    const int tid = threadIdx.x;     // 256
    const int i   = tid & 127, kh = tid >> 7;
    const int li  = lidx[0];
    const float* z = dlat + (n * 16 + li) * 512 + kh * 256;
    const float* a = aw + kh * 256 * 128 + i;
    float a0 = 0.f, a1 = 0.f, a2 = 0.f, a3 = 0.f;
    for (int k = 0; k < 256; k += 4) {
        a0 += z[k + 0] * a[(k + 0) * 128];
        a1 += z[k + 1] * a[(k + 1) * 128];
        a2 += z[k + 2] * a[(k + 2) * 128];
        a3 += z[k + 3] * a[(k + 3) * 128];
    }
    __shared__ float part[256];
    part[tid] = a0 + a1 + a2 + a3;
    __syncthreads();
    if (tid < 128)
        s_out[n * 128 + i] = (part[i] + part[i + 128]) * INV_SQRT_W + ab[i];
}

// ---------------- kernel W2: W2[i,o] = sum_t (cw[t,i,o]*inv)^2 ----------------
__global__ void k_w2(const float* __restrict__ cw, float* __restrict__ W2)
{
    const int idx = blockIdx.x * 256 + threadIdx.x;   // 16384 = i*128+o
    float acc = 0.f;
    #pragma unroll
    for (int t = 0; t < 9; ++t) {
        float w = cw[t * 16384 + idx];
        acc += w * w;
    }
    W2[idx] = acc * (INV_SQRT_KKC * INV_SQRT_KKC);
}

// ---------------- kernel D: d[n,o] = rsqrt(sum_i W2[i,o]*s2[n,i] + 1e-8) ----------------
__global__ void k_d(const float* __restrict__ W2,
                    const float* __restrict__ s_buf,
                    float* __restrict__ d_out)
{
    const int n = blockIdx.x;   // 8
    const int o = threadIdx.x;  // 128
    __shared__ float s2[128];
    float sv = s_buf[n * 128 + o];
    s2[o] = sv * sv;
    __syncthreads();
    float acc = 1e-8f;
    #pragma unroll 4
    for (int i = 0; i < 128; ++i)
        acc += W2[i * 128 + o] * s2[i];
    d_out[n * 128 + o] = 1.0f / sqrtf(acc);
}

// -------- kernel WMOD: 8KB weight stages, layout [k8:4][cout:128][8ci] bf16 --------
// stage s (0..35): phase p=s/18, sp=s-18p, tap=sp>>1, q2=sp&1, cibase=p*64+q2*32.
// element (k8, cout, j) = cw[tap][cibase+k8*8+j][cout] * inv * s[ci] * d[cout]
__global__ void k_wmod(const float* __restrict__ cw,
                       const float* __restrict__ s_buf,
                       const float* __restrict__ d_buf,
                       u16* __restrict__ wmod)
{
    const int b   = blockIdx.x;          // 288 = n*36 + s
    const int n   = b / 36;
    const int s   = b - n * 36;
    const int p   = (s >= 18) ? 1 : 0;
    const int sp  = s - p * 18;
    const int tap = sp >> 1, q2 = sp & 1;
    const int cibase = p * 64 + q2 * 32;
    const int tid = threadIdx.x;         // 256
    __shared__ float ssh[32], dsh[128];
    if (tid < 32)  ssh[tid] = s_buf[n * 128 + cibase + tid] * INV_SQRT_KKC;
    if (tid < 128) dsh[tid] = d_buf[n * 128 + tid];
    __syncthreads();
    u16* wt = wmod + ((size_t)b << 12);   // 4096 u16 per stage
    #pragma unroll
    for (int r = 0; r < 2; ++r) {
        int t2   = r * 256 + tid;         // 512 (k8,cout) pairs
        int k8   = t2 >> 7;
        int cout = t2 & 127;
        float dv = dsh[cout];
        u32 pk[4];
        #pragma unroll
        for (int jj = 0; jj < 4; ++jj) {
            int ci0 = k8 * 8 + jj * 2;
            float v0 = cw[((tap * 128 + cibase + ci0) << 7) + cout]     * ssh[ci0]     * dv;
            float v1 = cw[((tap * 128 + cibase + ci0 + 1) << 7) + cout] * ssh[ci0 + 1] * dv;
            pk[jj] = (u32)f2bf(v0) | ((u32)f2bf(v1) << 16);
        }
        *(uint4*)&wt[t2 * 8] = *(uint4*)pk;
    }
}

// ---------------- kernel CONV: implicit-GEMM 3x3 conv, ci-phased, 4 blocks/CU ----------------
// 256 threads = 4 waves (2x2); block tile 128 px (8h x 16w) x 128 cout.
// Wave: 64px x 64cout = 4 Mfrag x 4 Nfrag (acc[4][4]). K-step 32, 36 stages.
// xs holds a 64-ci half of the halo (22.5KB), restaged once; wsh dbuf 2x8KB.
// LDS total 39424B -> 4 blocks/CU = 16 waves/CU = 4 waves/SIMD.
__global__ __launch_bounds__(256, 4) void k_conv(
    const float* __restrict__ x,
    const float* __restrict__ noise,
    const float* __restrict__ conv_b,
    const float* __restrict__ nstr,
    const u16*   __restrict__ wmod,
    float* __restrict__ out)
{
    __shared__ __align__(16) u16 xs[11520];       // [q=rr*18+cc][64ci], XOR-swizzled
    __shared__ __align__(16) u16 wsh[2][4096];    // double-buffered 8KB weight stages

    const int bid0 = blockIdx.x;
    const int bid  = ((bid0 & 7) << 9) + (bid0 >> 3);   // XCD swizzle (4096%8==0, bijective)
    const int n   = bid >> 9;
    const int hb  = (bid >> 4) & 31;
    const int wb  = bid & 15;
    const int h0  = hb << 3, w0 = wb << 4;

    const int tid  = threadIdx.x;
    const int lane = tid & 63;
    const int wid  = tid >> 6;
    const int wm   = wid >> 1;
    const int wq   = wid & 1;
    const int lr   = lane & 15;
    const int kg   = lane >> 4;

    const float* xbase = x + ((size_t)n << 16) * 128;

    // ---- stage X halo half-tile (10 x 18 x 64ci), fp32 -> bf16, swizzled ----
    // phase ph: ci range [ph*64, ph*64+64)
    #define STAGE_X(ph)                                                              \
    for (int t = tid; t < 1440; t += 256) {                                          \
        int q  = t >> 3, k8 = t & 7;                                                 \
        int rr = q / 18, cc = q - rr * 18;                                           \
        int gh = h0 + rr - 1, gw = w0 + cc - 1;                                      \
        float v0=0.f,v1=0.f,v2=0.f,v3=0.f,v4=0.f,v5=0.f,v6=0.f,v7=0.f;               \
        if ((unsigned)gh < 256u && (unsigned)gw < 256u) {                            \
            const float* src = xbase + (size_t)((gh << 8) + gw) * 128                \
                               + (ph) * 64 + (k8 << 3);                              \
            float4 fa = *(const float4*)(src);                                       \
            float4 fb = *(const float4*)(src + 4);                                   \
            v0=fa.x; v1=fa.y; v2=fa.z; v3=fa.w; v4=fb.x; v5=fb.y; v6=fb.z; v7=fb.w;  \
        }                                                                            \
        uint4 pk;                                                                    \
        pk.x = (u32)f2bf(v0) | ((u32)f2bf(v1) << 16);                                \
        pk.y = (u32)f2bf(v2) | ((u32)f2bf(v3) << 16);                                \
        pk.z = (u32)f2bf(v4) | ((u32)f2bf(v5) << 16);                                \
        pk.w = (u32)f2bf(v6) | ((u32)f2bf(v7) << 16);                                \
        int dst = (q << 6) + ((k8 << 3) ^ ((q & 7) << 3));                           \
        *(uint4*)&xs[dst] = pk;                                                      \
    }

    STAGE_X(0)

    // ---- prologue: async-stage weight stage 0 into wsh[0] ----
    const u16* wn = wmod + ((size_t)(n * 36) << 12);
    {   // 8 chunks of 1KB; wave wid does chunks wid, wid+4
        #pragma unroll
        for (int t = 0; t < 2; ++t) {
            int chunk = wid + (t << 2);
            glds16(wn + (chunk << 9) + (lane << 3), &wsh[0][chunk << 9]);
        }
    }

    v4f acc[4][4];
    #pragma unroll
    for (int a = 0; a < 4; ++a)
        #pragma unroll
        for (int b2 = 0; b2 < 4; ++b2) {
            v4f zz = {0.f, 0.f, 0.f, 0.f};
            acc[a][b2] = zz;
        }

    __syncthreads();   // xs(phase0) ready + wsh[0] landed

    #pragma unroll 1
    for (int s = 0; s < 36; ++s) {
        const int c = s & 1;
        if (s < 35) {   // prefetch next weight stage
            const u16* sb = wn + ((size_t)(s + 1) << 12);
            #pragma unroll
            for (int t = 0; t < 2; ++t) {
                int chunk = wid + (t << 2);
                glds16(sb + (chunk << 9) + (lane << 3), &wsh[c ^ 1][chunk << 9]);
            }
        }
        const int sp  = (s >= 18) ? (s - 18) : s;
        const int tap = sp >> 1, q2 = sp & 1;
        const int th = tap / 3, tw = tap - th * 3;
        const int xoff = (q2 << 5) + (kg << 3);      // ci-local element offset

        v8bf af[4], bf_[4];
        #pragma unroll
        for (int mi = 0; mi < 4; ++mi) {
            int q = (wm * 4 + mi + th) * 18 + lr + tw;
            af[mi] = *(const v8bf*)&xs[(q << 6) + (xoff ^ ((q & 7) << 3))];
        }
        #pragma unroll
        for (int ni = 0; ni < 4; ++ni) {
            int o = wq * 64 + ni * 16 + lr;
            bf_[ni] = *(const v8bf*)&wsh[c][(kg << 10) + (o << 3)];
        }
        #pragma unroll
        for (int mi = 0; mi < 4; ++mi)
            #pragma unroll
            for (int ni = 0; ni < 4; ++ni)
                acc[mi][ni] = __builtin_amdgcn_mfma_f32_16x16x32_bf16(
                    af[mi], bf_[ni], acc[mi][ni], 0, 0, 0);

        __syncthreads();   // done with wsh[c]; wsh[c^1] drained (vmcnt at barrier)

        if (s == 17) {     // switch xs to ci 64..127
            STAGE_X(1)
            __syncthreads();
        }
    }

    // ---- epilogue: + noise*strength + bias, lrelu * sqrt(2) ----
    const float ns = nstr[0];
    #pragma unroll
    for (int mi = 0; mi < 4; ++mi) {
        const int h = h0 + wm * 4 + mi;
        #pragma unroll
        for (int j = 0; j < 4; ++j) {
            const int w  = w0 + kg * 4 + j;
            const float nz = noise[((n << 8) + h) * 256 + w] * ns;
            float* orow = out + (size_t)((((n << 8) + h) << 8) + w) * 128;
            #pragma unroll
            for (int ni = 0; ni < 4; ++ni) {
                const int cout = wq * 64 + ni * 16 + lr;
                float v = acc[mi][ni][j] + nz + conv_b[cout];
                v = (v < 0.f ? 0.2f * v : v) * LRELU_GAIN;
                orow[cout] = v;
            }
        }
    }
}

extern "C" void kernel_launch(void* const* d_in, const int* in_sizes, int n_in,
                              void* d_out, int out_size, void* d_ws, size_t ws_size,
                              hipStream_t stream) {
    const float* x     = (const float*)d_in[0];
    const float* dlat  = (const float*)d_in[1];
    const float* noise = (const float*)d_in[2];
    const float* aw    = (const float*)d_in[3];
    const float* ab    = (const float*)d_in[4];
    const float* cw    = (const float*)d_in[5];
    const float* cb    = (const float*)d_in[6];
    const float* nstr  = (const float*)d_in[7];
    const int*   lidx  = (const int*)d_in[8];
    float* out = (float*)d_out;

    float* s_buf = (float*)d_ws;                               // 4KB
    float* d_buf = (float*)((char*)d_ws + 4096);               // 4KB
    // W2 (64KB) aliases the wmod region: k_d finishes before k_wmod writes (stream order)
    float* W2    = (float*)((char*)d_ws + 8192);
    u16*   wmod  = (u16*)((char*)d_ws + 8192);                 // 8*36*4096*2B = 2.25MB

    k_w2  <<<64,  256, 0, stream>>>(cw, W2);
    k_s   <<<8,   256, 0, stream>>>(dlat, aw, ab, lidx, s_buf);
    k_d   <<<8,   128, 0, stream>>>(W2, s_buf, d_buf);
    k_wmod<<<288, 256, 0, stream>>>(cw, s_buf, d_buf, wmod);
    k_conv<<<4096,256, 0, stream>>>(x, noise, cb, nstr, wmod, out);
}

// Round 5
// 217.947 us; speedup vs baseline: 1.5304x; 1.0534x over previous
//
#include <hip/hip_runtime.h>

typedef unsigned short u16;
typedef unsigned int   u32;
typedef __bf16 v8bf __attribute__((ext_vector_type(8)));
typedef float  v4f  __attribute__((ext_vector_type(4)));

#define INV_SQRT_W   0.044194173824159216f   // 1/sqrt(512)
#define INV_SQRT_KKC 0.029462782549439483f   // 1/sqrt(3*3*128)
#define LRELU_GAIN   1.4142135623730951f

__device__ __forceinline__ u16 f2bf(float f) {
    u32 u = __float_as_uint(f);
    u = (u + 0x7fffu + ((u >> 16) & 1u)) >> 16;   // RNE
    return (u16)u;
}

__device__ __forceinline__ void glds16(const u16* g, u16* l) {
    __builtin_amdgcn_global_load_lds(
        (const __attribute__((address_space(1))) void*)g,
        (__attribute__((address_space(3))) void*)l, 16, 0, 0);
}

// ---------------- kernel S: s[n,i] = z @ (aw/sqrt(512)) + ab ----------------
__global__ void k_s(const float* __restrict__ dlat,
                    const float* __restrict__ aw,
                    const float* __restrict__ ab,
                    const int*   __restrict__ lidx,
                    float* __restrict__ s_out)
{
    const int n   = blockIdx.x;      // 8
    const int tid = threadIdx.x;     // 256
    const int i   = tid & 127, kh = tid >> 7;
    const int li  = lidx[0];
    const float* z = dlat + (n * 16 + li) * 512 + kh * 256;
    const float* a = aw + kh * 256 * 128 + i;
    float a0 = 0.f, a1 = 0.f, a2 = 0.f, a3 = 0.f;
    for (int k = 0; k < 256; k += 4) {
        a0 += z[k + 0] * a[(k + 0) * 128];
        a1 += z[k + 1] * a[(k + 1) * 128];
        a2 += z[k + 2] * a[(k + 2) * 128];
        a3 += z[k + 3] * a[(k + 3) * 128];
    }
    __shared__ float part[256];
    part[tid] = a0 + a1 + a2 + a3;
    __syncthreads();
    if (tid < 128)
        s_out[n * 128 + i] = (part[i] + part[i + 128]) * INV_SQRT_W + ab[i];
}

// ---------------- kernel W2: W2[i,o] = sum_t (cw[t,i,o]*inv)^2 ----------------
__global__ void k_w2(const float* __restrict__ cw, float* __restrict__ W2)
{
    const int idx = blockIdx.x * 256 + threadIdx.x;   // 16384 = i*128+o
    float acc = 0.f;
    #pragma unroll
    for (int t = 0; t < 9; ++t) {
        float w = cw[t * 16384 + idx];
        acc += w * w;
    }
    W2[idx] = acc * (INV_SQRT_KKC * INV_SQRT_KKC);
}

// ---------------- kernel D: d[n,o] = rsqrt(sum_i W2[i,o]*s2[n,i] + 1e-8) ----------------
__global__ void k_d(const float* __restrict__ W2,
                    const float* __restrict__ s_buf,
                    float* __restrict__ d_out)
{
    const int n = blockIdx.x;   // 8
    const int o = threadIdx.x;  // 128
    __shared__ float s2[128];
    float sv = s_buf[n * 128 + o];
    s2[o] = sv * sv;
    __syncthreads();
    float acc = 1e-8f;
    #pragma unroll 4
    for (int i = 0; i < 128; ++i)
        acc += W2[i * 128 + o] * s2[i];
    d_out[n * 128 + o] = 1.0f / sqrtf(acc);
}

// -------- kernel WMOD: 8KB weight stages, layout [g:4][cout:128][8ci] bf16 --------
// stage s (0..35): p=s/18, sp=s-18p, tap=sp>>1, q2=sp&1, cibase=p*64+q2*32.
// elem(g, cout, j) = cw[tap][cibase+g*8+j][cout] * inv * s[ci] * d[cout]
__global__ void k_wmod(const float* __restrict__ cw,
                       const float* __restrict__ s_buf,
                       const float* __restrict__ d_buf,
                       u16* __restrict__ wmod)
{
    const int b   = blockIdx.x;          // 288 = n*36 + s
    const int n   = b / 36;
    const int s   = b - n * 36;
    const int p   = (s >= 18) ? 1 : 0;
    const int sp  = s - p * 18;
    const int tap = sp >> 1, q2 = sp & 1;
    const int cibase = p * 64 + q2 * 32;
    const int tid = threadIdx.x;         // 256
    __shared__ float ssh[32], dsh[128];
    if (tid < 32)  ssh[tid] = s_buf[n * 128 + cibase + tid] * INV_SQRT_KKC;
    if (tid < 128) dsh[tid] = d_buf[n * 128 + tid];
    __syncthreads();
    u16* wt = wmod + ((size_t)b << 12);   // 4096 u16 per stage
    #pragma unroll
    for (int r = 0; r < 2; ++r) {
        int t2   = r * 256 + tid;         // 512 (g,cout) pairs
        int g    = t2 >> 7;
        int cout = t2 & 127;
        float dv = dsh[cout];
        u32 pk[4];
        #pragma unroll
        for (int jj = 0; jj < 4; ++jj) {
            int cl = g * 8 + jj * 2;
            float v0 = cw[((tap * 128 + cibase + cl) << 7) + cout]     * ssh[cl]     * dv;
            float v1 = cw[((tap * 128 + cibase + cl + 1) << 7) + cout] * ssh[cl + 1] * dv;
            pk[jj] = (u32)f2bf(v0) | ((u32)f2bf(v1) << 16);
        }
        *(uint4*)&wt[(g << 10) + (cout << 3)] = *(uint4*)pk;
    }
}

// ---------------- kernel CONV: implicit-GEMM 3x3 conv, immediate-offset LDS ----------------
// 256 threads = 4 waves (2x2); block tile 128 px (8h x 16w) x 128 cout.
// xs[g:8][q:180][8ci]  (granule-major: A-reads contiguous, addr = base + imm)
// wsh[c][g:4][cout:128][8ci] (B-reads contiguous, addr = base + imm)
// 36 fully-unrolled stages: tap/q2/buffer parity compile-time -> ~0 main-loop VALU.
__global__ __launch_bounds__(256, 4) void k_conv(
    const float* __restrict__ x,
    const float* __restrict__ noise,
    const float* __restrict__ conv_b,
    const float* __restrict__ nstr,
    const u16*   __restrict__ wmod,
    float* __restrict__ out)
{
    __shared__ __align__(16) u16 xs[11520];       // 8 slabs x 180 q x 8 ci = 23040B
    __shared__ __align__(16) u16 wsh[8192];       // 2 buffers x [4][128][8] = 16KB

    const int bid0 = blockIdx.x;
    const int bid  = ((bid0 & 7) << 9) + (bid0 >> 3);   // XCD swizzle (4096%8==0, bijective)
    const int n   = bid >> 9;
    const int hb  = (bid >> 4) & 31;
    const int wb  = bid & 15;
    const int h0  = hb << 3, w0 = wb << 4;

    const int tid  = threadIdx.x;
    const int lane = tid & 63;
    const int wid  = tid >> 6;
    const int wm   = wid >> 1;
    const int wq   = wid & 1;
    const int lr   = lane & 15;
    const int kg   = lane >> 4;

    const float* xbase = x + ((size_t)n << 16) * 128;

    // per-lane base addresses (u16 units), all stage variation goes to immediates
    u16* const a_base = &xs[kg * 1440 + wm * 576 + lr * 8];
    u16* const b_base = &wsh[kg * 1024 + (wq * 64 + lr) * 8];

    // ---- stage X halo half-tile (10 x 18 x 64ci) fp32 -> bf16, granule-major ----
    #define STAGE_X(ph)                                                              \
    for (int t = tid; t < 1440; t += 256) {                                          \
        int q = t >> 3, g = t & 7;                                                   \
        int rr = q / 18, cc = q - rr * 18;                                           \
        int gh = h0 + rr - 1, gw = w0 + cc - 1;                                      \
        float v0=0.f,v1=0.f,v2=0.f,v3=0.f,v4=0.f,v5=0.f,v6=0.f,v7=0.f;               \
        if ((unsigned)gh < 256u && (unsigned)gw < 256u) {                            \
            const float* src = xbase + (size_t)((gh << 8) + gw) * 128                \
                               + (ph) * 64 + (g << 3);                               \
            float4 fa = *(const float4*)(src);                                       \
            float4 fb = *(const float4*)(src + 4);                                   \
            v0=fa.x; v1=fa.y; v2=fa.z; v3=fa.w; v4=fb.x; v5=fb.y; v6=fb.z; v7=fb.w;  \
        }                                                                            \
        v8bf pk;                                                                     \
        pk[0]=(__bf16)v0; pk[1]=(__bf16)v1; pk[2]=(__bf16)v2; pk[3]=(__bf16)v3;      \
        pk[4]=(__bf16)v4; pk[5]=(__bf16)v5; pk[6]=(__bf16)v6; pk[7]=(__bf16)v7;      \
        *(v8bf*)&xs[g * 1440 + q * 8] = pk;                                          \
    }

    STAGE_X(0)

    // ---- prologue: async-stage weight stage 0 into buffer 0 ----
    const u16* wn = wmod + ((size_t)(n * 36) << 12);
    #pragma unroll
    for (int t = 0; t < 2; ++t) {
        int chunk = wid + (t << 2);
        glds16(wn + (chunk << 9) + (lane << 3), &wsh[chunk << 9]);
    }

    v4f acc[4][4];
    #pragma unroll
    for (int a = 0; a < 4; ++a)
        #pragma unroll
        for (int b2 = 0; b2 < 4; ++b2) {
            v4f zz = {0.f, 0.f, 0.f, 0.f};
            acc[a][b2] = zz;
        }

    __syncthreads();   // xs(phase0) ready + wsh buf0 landed

    #pragma unroll
    for (int s = 0; s < 36; ++s) {
        const int c = s & 1;                 // compile-time after unroll
        if (s < 35) {                        // prefetch next weight stage
            const u16* sb = wn + ((size_t)(s + 1) << 12);
            #pragma unroll
            for (int t = 0; t < 2; ++t) {
                int chunk = wid + (t << 2);
                glds16(sb + (chunk << 9) + (lane << 3), &wsh[((c ^ 1) << 12) + (chunk << 9)]);
            }
        }
        const int sp  = (s >= 18) ? (s - 18) : s;
        const int tap = sp >> 1, q2 = sp & 1;
        const int th  = tap / 3, tw = tap - th * 3;

        v8bf af[4], bf_[4];
        #pragma unroll
        for (int mi = 0; mi < 4; ++mi)
            af[mi] = *(const v8bf*)(a_base + q2 * 5760 + (mi + th) * 144 + tw * 8);
        #pragma unroll
        for (int ni = 0; ni < 4; ++ni)
            bf_[ni] = *(const v8bf*)(b_base + (c << 12) + (ni << 7));
        #pragma unroll
        for (int mi = 0; mi < 4; ++mi)
            #pragma unroll
            for (int ni = 0; ni < 4; ++ni)
                acc[mi][ni] = __builtin_amdgcn_mfma_f32_16x16x32_bf16(
                    af[mi], bf_[ni], acc[mi][ni], 0, 0, 0);

        __syncthreads();   // done with buf c; buf c^1 glds drained at barrier

        if (s == 17) {     // switch xs to ci 64..127
            STAGE_X(1)
            __syncthreads();
        }
    }

    // ---- epilogue: + noise*strength + bias, lrelu * sqrt(2) ----
    const float ns = nstr[0];
    #pragma unroll
    for (int mi = 0; mi < 4; ++mi) {
        const int h = h0 + wm * 4 + mi;
        #pragma unroll
        for (int j = 0; j < 4; ++j) {
            const int w  = w0 + kg * 4 + j;
            const float nz = noise[((n << 8) + h) * 256 + w] * ns;
            float* orow = out + (size_t)((((n << 8) + h) << 8) + w) * 128;
            #pragma unroll
            for (int ni = 0; ni < 4; ++ni) {
                const int cout = wq * 64 + ni * 16 + lr;
                float v = acc[mi][ni][j] + nz + conv_b[cout];
                v = (v < 0.f ? 0.2f * v : v) * LRELU_GAIN;
                orow[cout] = v;
            }
        }
    }
}

extern "C" void kernel_launch(void* const* d_in, const int* in_sizes, int n_in,
                              void* d_out, int out_size, void* d_ws, size_t ws_size,
                              hipStream_t stream) {
    const float* x     = (const float*)d_in[0];
    const float* dlat  = (const float*)d_in[1];
    const float* noise = (const float*)d_in[2];
    const float* aw    = (const float*)d_in[3];
    const float* ab    = (const float*)d_in[4];
    const float* cw    = (const float*)d_in[5];
    const float* cb    = (const float*)d_in[6];
    const float* nstr  = (const float*)d_in[7];
    const int*   lidx  = (const int*)d_in[8];
    float* out = (float*)d_out;

    float* s_buf = (float*)d_ws;                               // 4KB
    float* d_buf = (float*)((char*)d_ws + 4096);               // 4KB
    // W2 (64KB) aliases the wmod region: k_d finishes before k_wmod writes (stream order)
    float* W2    = (float*)((char*)d_ws + 8192);
    u16*   wmod  = (u16*)((char*)d_ws + 8192);                 // 8*36*4096*2B = 2.25MB

    k_w2  <<<64,  256, 0, stream>>>(cw, W2);
    k_s   <<<8,   256, 0, stream>>>(dlat, aw, ab, lidx, s_buf);
    k_d   <<<8,   128, 0, stream>>>(W2, s_buf, d_buf);
    k_wmod<<<288, 256, 0, stream>>>(cw, s_buf, d_buf, wmod);
    k_conv<<<4096,256, 0, stream>>>(x, noise, cb, nstr, wmod, out);
}